// Round 2
// baseline (690.188 us; speedup 1.0000x reference)
//
#include <hip/hip_runtime.h>
#include <hip/hip_bf16.h>

// OrdinalRegressionLoss: B x 256 fp32 logits, int targets (0..255).
// row_sum = sum_{k=0..254} softplus( (k<t) ? cum_k : -cum_k ); out = mean over rows.
// Identity: softplus(z) = z/2 + |z|/2 + log1p(exp(-|z|)), so
//   row_sum = 0.5*(2*pre - sum_c) + 0.5*sum_abs + sum_log1p,  pre = sum_{k<t} cum_k.
// One wave per row-slice: lane i float4-loads cols 4i..4i+3 (coalesced 1KiB/row/wave).
// Cumsum via DPP scan (no ds_permute). 4 log1p fused into one log of a product.
// 8 rows/wave, unrolled + prefetch -> >=2 loads in flight. Memory-bound target ~85us.

#define WAVE 64
#define BLOCK 256
#define WPB (BLOCK / WAVE)
#define ROWS 8
#define NCLASS 256

// wave64 inclusive add-scan via DPP (classic GCN idiom), 12 VALU insts, no LDS.
__device__ __forceinline__ float wave_incl_scan(float s) {
    int t;
    t = __builtin_amdgcn_update_dpp(0, __float_as_int(s), 0x111, 0xf, 0xf, true); s += __int_as_float(t); // row_shr:1
    t = __builtin_amdgcn_update_dpp(0, __float_as_int(s), 0x112, 0xf, 0xf, true); s += __int_as_float(t); // row_shr:2
    t = __builtin_amdgcn_update_dpp(0, __float_as_int(s), 0x114, 0xf, 0xf, true); s += __int_as_float(t); // row_shr:4
    t = __builtin_amdgcn_update_dpp(0, __float_as_int(s), 0x118, 0xf, 0xf, true); s += __int_as_float(t); // row_shr:8
    t = __builtin_amdgcn_update_dpp(0, __float_as_int(s), 0x142, 0xa, 0xf, true); s += __int_as_float(t); // bcast15 -> rows 1,3
    t = __builtin_amdgcn_update_dpp(0, __float_as_int(s), 0x143, 0xc, 0xf, true); s += __int_as_float(t); // bcast31 -> rows 2,3
    return s;
}

template <bool EXACT>
__global__ __launch_bounds__(BLOCK, 4) void ordloss_main(
        const float* __restrict__ logits,
        const int*   __restrict__ targets,
        double*      __restrict__ partials,
        int B) {
    const int lane = threadIdx.x & (WAVE - 1);
    const int wib  = threadIdx.x >> 6;
    const long long rowBase = ((long long)blockIdx.x * WPB + wib) * ROWS;
    const float lm = (lane == WAVE - 1) ? 0.0f : 1.0f;  // kill k=255 contributions
    const int k0 = lane << 2;
    const float LOG2E = 1.4426950408889634f;

    float acc_lin = 0.0f, acc_abs = 0.0f, acc_log = 0.0f;

    const float4* p = reinterpret_cast<const float4*>(logits) + rowBase * (NCLASS / 4) + lane;

    float4 v = make_float4(0, 0, 0, 0);
    int t = 0;
    if (EXACT || rowBase < B) { v = p[0]; t = targets[rowBase]; }

    #pragma unroll
    for (int i = 0; i < ROWS; ++i) {
        const long long row = rowBase + i;
        if (!EXACT && row >= B) break;

        float4 vn; int tn = 0;
        if (i + 1 < ROWS) {
            if (EXACT || row + 1 < B) { vn = p[(i + 1) * (NCLASS / 4)]; tn = targets[row + 1]; }
        }

        // local inclusive prefix of the 4 elements
        const float l0 = v.x;
        const float l1 = l0 + v.y;
        const float l2 = l1 + v.z;
        const float l3 = l2 + v.w;

        const float incl = wave_incl_scan(l3);
        const float excl = incl - l3;

        const float c0 = excl + l0;
        const float c1 = excl + l1;
        const float c2 = excl + l2;
        const float c3 = excl + l3;

        const float a0 = fabsf(c0), a1 = fabsf(c1), a2 = fabsf(c2), a3 = fabsf(c3);

        // u = exp(-a) via hw exp2; lane63's u3 masked to 0 so its factor is 1
        const float u0 = __builtin_amdgcn_exp2f(-a0 * LOG2E);
        const float u1 = __builtin_amdgcn_exp2f(-a1 * LOG2E);
        const float u2 = __builtin_amdgcn_exp2f(-a2 * LOG2E);
        const float u3 = __builtin_amdgcn_exp2f(-a3 * LOG2E) * lm;

        float pr = 1.0f + u0;
        pr = __builtin_fmaf(pr, u1, pr);   // pr *= (1+u1)
        pr = __builtin_fmaf(pr, u2, pr);
        pr = __builtin_fmaf(pr, u3, pr);
        acc_log += __logf(pr);             // = sum log1p(u_i)

        const float c3m = c3 * lm;
        acc_abs += a0 + a1 + a2 + a3 * lm;

        const float sum_c = c0 + c1 + c2 + c3m;
        float pre = 0.0f;
        pre += (k0 + 0 < t) ? c0 : 0.0f;
        pre += (k0 + 1 < t) ? c1 : 0.0f;
        pre += (k0 + 2 < t) ? c2 : 0.0f;
        pre += (k0 + 3 < t) ? c3 : 0.0f;   // k=255 < t is impossible (t<=255): auto-masked
        acc_lin += 2.0f * pre - sum_c;

        v = vn; t = tn;
    }

    // per-lane combine in double, then wave + block reduce
    double d = 0.5 * ((double)acc_lin + (double)acc_abs) + (double)acc_log;
    #pragma unroll
    for (int off = 32; off > 0; off >>= 1)
        d += __shfl_down(d, off, WAVE);

    __shared__ double sd[WPB];
    if (lane == 0) sd[wib] = d;
    __syncthreads();
    if (threadIdx.x == 0) {
        double s = 0.0;
        #pragma unroll
        for (int w = 0; w < WPB; ++w) s += sd[w];
        partials[blockIdx.x] = s;
    }
}

__global__ __launch_bounds__(256) void ordloss_reduce(
        const double* __restrict__ partials, int n,
        float* __restrict__ out, double invB) {
    __shared__ double smem[256];
    double s = 0.0;
    for (int i = threadIdx.x; i < n; i += 256) s += partials[i];
    smem[threadIdx.x] = s;
    __syncthreads();
    for (int st = 128; st > 0; st >>= 1) {
        if (threadIdx.x < st) smem[threadIdx.x] += smem[threadIdx.x + st];
        __syncthreads();
    }
    if (threadIdx.x == 0) out[0] = (float)(smem[0] * invB);
}

extern "C" void kernel_launch(void* const* d_in, const int* in_sizes, int n_in,
                              void* d_out, int out_size, void* d_ws, size_t ws_size,
                              hipStream_t stream) {
    const float* logits   = (const float*)d_in[0];
    const int*   targets  = (const int*)d_in[1];
    float*       out      = (float*)d_out;
    double*      partials = (double*)d_ws;

    const int B = in_sizes[1];
    const int rows_per_block = WPB * ROWS;              // 32
    const int NB = (B + rows_per_block - 1) / rows_per_block;

    if (B % rows_per_block == 0)
        ordloss_main<true><<<NB, BLOCK, 0, stream>>>(logits, targets, partials, B);
    else
        ordloss_main<false><<<NB, BLOCK, 0, stream>>>(logits, targets, partials, B);

    ordloss_reduce<<<1, 256, 0, stream>>>(partials, NB, out, 1.0 / (double)B);
}

// Round 3
// 683.741 us; speedup vs baseline: 1.0094x; 1.0094x over previous
//
#include <hip/hip_runtime.h>
#include <hip/hip_bf16.h>

// OrdinalRegressionLoss: B x 256 fp32 logits, int targets (0..255).
// row_sum = sum_{k=0..254} softplus( (k<t) ? cum_k : -cum_k ); out = mean over rows.
// Identity: softplus(z) = z/2 + |z|/2 + log1p(exp(-|z|)) =>
//   row_sum = 0.5*(2*pre - sum_c) + 0.5*sum_abs + sum_log1p,  pre = sum_{k<t} cum_k.
// One wave per row: lane i float4-loads cols 4i..4i+3 (coalesced 1KiB/row/wave).
// R3 change: batch-load ALL 8 rows (+targets) up-front -> 16 vmem ops in flight per
// wave (~8KiB), attacking the load-latency plateau seen in R1/R2 (both ~686us).
// Cumsum via DPP wave scan; 4 log1p fused into one log of a product.

#define WAVE 64
#define BLOCK 256
#define WPB (BLOCK / WAVE)
#define ROWS 8
#define NCLASS 256

// wave64 inclusive add-scan via DPP, 12 VALU insts, no LDS. (verified R2, absmax 0)
__device__ __forceinline__ float wave_incl_scan(float s) {
    int t;
    t = __builtin_amdgcn_update_dpp(0, __float_as_int(s), 0x111, 0xf, 0xf, true); s += __int_as_float(t); // row_shr:1
    t = __builtin_amdgcn_update_dpp(0, __float_as_int(s), 0x112, 0xf, 0xf, true); s += __int_as_float(t); // row_shr:2
    t = __builtin_amdgcn_update_dpp(0, __float_as_int(s), 0x114, 0xf, 0xf, true); s += __int_as_float(t); // row_shr:4
    t = __builtin_amdgcn_update_dpp(0, __float_as_int(s), 0x118, 0xf, 0xf, true); s += __int_as_float(t); // row_shr:8
    t = __builtin_amdgcn_update_dpp(0, __float_as_int(s), 0x142, 0xa, 0xf, true); s += __int_as_float(t); // bcast15 -> rows 1,3
    t = __builtin_amdgcn_update_dpp(0, __float_as_int(s), 0x143, 0xc, 0xf, true); s += __int_as_float(t); // bcast31 -> rows 2,3
    return s;
}

template <bool EXACT>
__global__ __launch_bounds__(BLOCK) void ordloss_main(
        const float* __restrict__ logits,
        const int*   __restrict__ targets,
        double*      __restrict__ partials,
        int B) {
    const int lane = threadIdx.x & (WAVE - 1);
    const int wib  = threadIdx.x >> 6;
    const long long rowBase = ((long long)blockIdx.x * WPB + wib) * ROWS;
    const float lm = (lane == WAVE - 1) ? 0.0f : 1.0f;  // kill k=255 contributions
    const int k0 = lane << 2;
    const float LOG2E = 1.4426950408889634f;

    const float4* p = reinterpret_cast<const float4*>(logits) + rowBase * (NCLASS / 4) + lane;

    // ---- batch load phase: 8 dwordx4 + 8 dword loads issued back-to-back ----
    float4 v[ROWS];
    int    tg[ROWS];
    #pragma unroll
    for (int i = 0; i < ROWS; ++i) {
        if (EXACT || rowBase + i < B) {
            v[i]  = p[i * (NCLASS / 4)];
            tg[i] = targets[rowBase + i];
        } else {
            v[i] = make_float4(0.f, 0.f, 0.f, 0.f);
            tg[i] = 0;
        }
    }

    // ---- compute phase ----
    float acc_lin = 0.0f, acc_abs = 0.0f, acc_log = 0.0f;
    #pragma unroll
    for (int i = 0; i < ROWS; ++i) {
        if (!EXACT && rowBase + i >= B) break;   // padded rows must not contribute
        const int t = tg[i];

        const float l0 = v[i].x;
        const float l1 = l0 + v[i].y;
        const float l2 = l1 + v[i].z;
        const float l3 = l2 + v[i].w;

        const float incl = wave_incl_scan(l3);
        const float excl = incl - l3;

        const float c0 = excl + l0;
        const float c1 = excl + l1;
        const float c2 = excl + l2;
        const float c3 = excl + l3;

        const float a0 = fabsf(c0), a1 = fabsf(c1), a2 = fabsf(c2), a3 = fabsf(c3);

        // u = exp(-a); lane63's u3 masked to 0 so its log1p factor is 1
        const float u0 = __builtin_amdgcn_exp2f(-a0 * LOG2E);
        const float u1 = __builtin_amdgcn_exp2f(-a1 * LOG2E);
        const float u2 = __builtin_amdgcn_exp2f(-a2 * LOG2E);
        const float u3 = __builtin_amdgcn_exp2f(-a3 * LOG2E) * lm;

        float pr = 1.0f + u0;
        pr = __builtin_fmaf(pr, u1, pr);   // pr *= (1+u1)
        pr = __builtin_fmaf(pr, u2, pr);
        pr = __builtin_fmaf(pr, u3, pr);
        acc_log += __logf(pr);             // = sum_j log1p(u_j)

        acc_abs += a0 + a1 + a2 + a3 * lm;

        const float sum_c = c0 + c1 + c2 + c3 * lm;
        float pre = 0.0f;
        pre += (k0 + 0 < t) ? c0 : 0.0f;
        pre += (k0 + 1 < t) ? c1 : 0.0f;
        pre += (k0 + 2 < t) ? c2 : 0.0f;
        pre += (k0 + 3 < t) ? c3 : 0.0f;   // k=255 < t impossible (t<=255): auto-masked
        acc_lin += 2.0f * pre - sum_c;
    }

    // per-lane combine in double, then wave + block reduce
    double d = 0.5 * ((double)acc_lin + (double)acc_abs) + (double)acc_log;
    #pragma unroll
    for (int off = 32; off > 0; off >>= 1)
        d += __shfl_down(d, off, WAVE);

    __shared__ double sd[WPB];
    if (lane == 0) sd[wib] = d;
    __syncthreads();
    if (threadIdx.x == 0) {
        double s = 0.0;
        #pragma unroll
        for (int w = 0; w < WPB; ++w) s += sd[w];
        partials[blockIdx.x] = s;
    }
}

__global__ __launch_bounds__(512) void ordloss_reduce(
        const double* __restrict__ partials, int n,
        float* __restrict__ out, double invB) {
    __shared__ double smem[512];
    double s = 0.0;
    for (int i = threadIdx.x; i < n; i += 512) s += partials[i];
    smem[threadIdx.x] = s;
    __syncthreads();
    for (int st = 256; st > 0; st >>= 1) {
        if (threadIdx.x < st) smem[threadIdx.x] += smem[threadIdx.x + st];
        __syncthreads();
    }
    if (threadIdx.x == 0) out[0] = (float)(smem[0] * invB);
}

extern "C" void kernel_launch(void* const* d_in, const int* in_sizes, int n_in,
                              void* d_out, int out_size, void* d_ws, size_t ws_size,
                              hipStream_t stream) {
    const float* logits   = (const float*)d_in[0];
    const int*   targets  = (const int*)d_in[1];
    float*       out      = (float*)d_out;
    double*      partials = (double*)d_ws;

    const int B = in_sizes[1];
    const int rows_per_block = WPB * ROWS;              // 32
    const int NB = (B + rows_per_block - 1) / rows_per_block;

    if (B % rows_per_block == 0)
        ordloss_main<true><<<NB, BLOCK, 0, stream>>>(logits, targets, partials, B);
    else
        ordloss_main<false><<<NB, BLOCK, 0, stream>>>(logits, targets, partials, B);

    ordloss_reduce<<<1, 512, 0, stream>>>(partials, NB, out, 1.0 / (double)B);
}